// Round 1
// baseline (11668.808 us; speedup 1.0000x reference)
//
#include <hip/hip_runtime.h>

static constexpr int HN = 512;
static constexpr float HINF = 1e9f;

// cost = W_SIM*sim + W_IOU*iou with W=1.0 -> exact elementwise add (matches jnp fp32).
__global__ void cost_add_kernel(const float* __restrict__ sim,
                                const float* __restrict__ iou,
                                float* __restrict__ cost) {
    int idx = blockIdx.x * blockDim.x + threadIdx.x;
    if (idx < HN * HN / 4) {
        const float4* s4 = reinterpret_cast<const float4*>(sim);
        const float4* i4 = reinterpret_cast<const float4*>(iou);
        float4 a = s4[idx];
        float4 b = i4[idx];
        float4 c;
        c.x = a.x + b.x;
        c.y = a.y + b.y;
        c.z = a.z + b.z;
        c.w = a.w + b.w;
        reinterpret_cast<float4*>(cost)[idx] = c;
    }
}

// Exact mirror of the reference JV (e-maxx) Hungarian, 1-indexed, minimizing -cost.
// Single wave (64 lanes), each lane owns 8 consecutive columns (cols 1..512).
// Wave-synchronous: uniform control flow, shfl-based argmin, LDS only for u/p/way.
__global__ void __launch_bounds__(64, 1) hungarian_kernel(const float* __restrict__ cost,
                                                          float* __restrict__ out) {
    __shared__ float u_s[HN + 1];
    __shared__ int p_s[HN + 1];
    __shared__ int way_s[HN + 1];

    const int lane = threadIdx.x;

    for (int k = lane; k <= HN; k += 64) {
        u_s[k] = 0.0f;
        p_s[k] = 0;
        way_s[k] = 0;
    }
    __syncthreads();

    float v[8];
#pragma unroll
    for (int k = 0; k < 8; ++k) v[k] = 0.0f;

    for (int i = 1; i <= HN; ++i) {
        if (lane == 0) p_s[0] = i;
        __syncthreads();

        float minv[8];
        int way[8];
        int p_own[8];
        unsigned usedmask = 0u;
#pragma unroll
        for (int k = 0; k < 8; ++k) {
            minv[k] = HINF;
            way[k] = 0;
            p_own[k] = p_s[8 * lane + k + 1];  // matched row of my col (stable during Dijkstra)
        }

        int j0 = 0;
        int i0 = i;  // p_s[0] == i
        int jfin = 0;
        while (true) {
            // used[j0] = True (col 0 is virtual: no lane owns it)
            int k0 = j0 - 1;
            if ((k0 >> 3) == lane) usedmask |= (1u << (k0 & 7));

            float u_i0 = u_s[i0];
            const float4* r4 = reinterpret_cast<const float4*>(cost + (size_t)(i0 - 1) * HN);
            float4 ra = r4[2 * lane];
            float4 rb = r4[2 * lane + 1];
            float c[8] = {ra.x, ra.y, ra.z, ra.w, rb.x, rb.y, rb.z, rb.w};

            float bv = HINF;
            int bj = 0x7FFFFFFF;
#pragma unroll
            for (int k = 0; k < 8; ++k) {
                // cur = costp[i0][j] - u[i0] - v[j], costp = -cost (exact negation)
                float cur = (-c[k] - u_i0) - v[k];
                bool used = (usedmask >> k) & 1u;
                if (!used && cur < minv[k]) {
                    minv[k] = cur;
                    way[k] = j0;
                }
                float cand = used ? HINF : minv[k];
                if (cand < bv) {  // strict < with k ascending -> first min (jnp.argmin)
                    bv = cand;
                    bj = 8 * lane + k + 1;
                }
            }
            // lexicographic (val, idx) min butterfly across the wave
#pragma unroll
            for (int off = 1; off < 64; off <<= 1) {
                float ov = __shfl_xor(bv, off, 64);
                int oj = __shfl_xor(bj, off, 64);
                if (ov < bv || (ov == bv && oj < bj)) {
                    bv = ov;
                    bj = oj;
                }
            }
            const float delta = bv;
            const int j1 = bj;

            // dual updates (exactly one fp add/sub per entry, as in the reference)
            if (lane == 0) u_s[i] += delta;  // col 0 is always used: u[p[0]] += delta
#pragma unroll
            for (int k = 0; k < 8; ++k) {
                if ((usedmask >> k) & 1u) {
                    v[k] -= delta;
                    u_s[p_own[k]] += delta;  // matched rows are distinct -> race-free
                } else {
                    minv[k] -= delta;
                }
            }

            int pj = p_s[j1];
            j0 = j1;
            if (pj == 0) {
                jfin = j1;
                break;
            }
            i0 = pj;
        }

        // dump way registers so lane 0 can walk the alternating path
#pragma unroll
        for (int k = 0; k < 8; ++k) way_s[8 * lane + k + 1] = way[k];
        __syncthreads();
        if (lane == 0) {
            int jw = jfin;
            while (jw != 0) {
                int jn = way_s[jw];
                p_s[jw] = p_s[jn];
                jw = jn;
            }
        }
        __syncthreads();
    }

    // outputs: [cost (512x512)] [row_ind (512)] [col_ind (512)], all as float32 values
    float* rowo = out + HN * HN;
    float* colo = rowo + HN;
#pragma unroll
    for (int k = 0; k < 8; ++k) {
        int r = 8 * lane + k;
        rowo[r] = (float)r;
        int j = r + 1;        // col j (1-indexed)
        int prow = p_s[j];    // row matched to col j, in 1..512
        colo[prow - 1] = (float)(j - 1);
    }
}

extern "C" void kernel_launch(void* const* d_in, const int* in_sizes, int n_in,
                              void* d_out, int out_size, void* d_ws, size_t ws_size,
                              hipStream_t stream) {
    const float* sim = (const float*)d_in[0];
    const float* iou = (const float*)d_in[1];
    float* out = (float*)d_out;

    cost_add_kernel<<<(HN * HN / 4 + 255) / 256, 256, 0, stream>>>(sim, iou, out);
    hungarian_kernel<<<1, 64, 0, stream>>>(out, out);
}

// Round 2
// 10046.323 us; speedup vs baseline: 1.1615x; 1.1615x over previous
//
#include <hip/hip_runtime.h>

static constexpr int HN = 512;
static constexpr float HINF = 1e9f;

// cost = sim + iou (exact fp32 add, matches jnp)
__global__ void cost_add_kernel(const float* __restrict__ sim,
                                const float* __restrict__ iou,
                                float* __restrict__ cost) {
    int idx = blockIdx.x * blockDim.x + threadIdx.x;
    if (idx < HN * HN / 4) {
        const float4* s4 = reinterpret_cast<const float4*>(sim);
        const float4* i4 = reinterpret_cast<const float4*>(iou);
        float4 a = s4[idx];
        float4 b = i4[idx];
        float4 c;
        c.x = a.x + b.x;
        c.y = a.y + b.y;
        c.z = a.z + b.z;
        c.w = a.w + b.w;
        reinterpret_cast<float4*>(cost)[idx] = c;
    }
}

// Lexicographic (val, idx) min combine step via DPP; payload (jp, u) selected consistently.
// After shr 1,2,4,8 + bcast15 + bcast31, lane 63 holds the full-wave reduction.
#define DPP_STEP(ctrl)                                                                        \
    {                                                                                         \
        int ovi = __builtin_amdgcn_update_dpp(__float_as_int(bv), __float_as_int(bv), (ctrl), \
                                              0xF, 0xF, false);                               \
        int oj = __builtin_amdgcn_update_dpp(bj, bj, (ctrl), 0xF, 0xF, false);                \
        int oui = __builtin_amdgcn_update_dpp(__float_as_int(bu), __float_as_int(bu), (ctrl), \
                                              0xF, 0xF, false);                               \
        float ov = __int_as_float(ovi);                                                       \
        bool take = (ov < bv) || ((ov == bv) && (oj < bj));                                   \
        if (take) {                                                                           \
            bv = ov;                                                                          \
            bj = oj;                                                                          \
            bu = __int_as_float(oui);                                                         \
        }                                                                                     \
    }

// Exact mirror of the reference JV (e-maxx) Hungarian on -cost, single wave of 64 lanes,
// each lane owning 8 consecutive columns. Inner loop touches NO LDS: duals for free cols
// are phase-invariant, so (p_own, u_own) live in registers and ride the argmin payload.
__global__ void __launch_bounds__(64, 1) hungarian_kernel(const float* __restrict__ cost,
                                                          float* __restrict__ out) {
    __shared__ float u_s[HN + 1];
    __shared__ int p_s[HN + 1];
    __shared__ int way_s[HN + 1];

    const int lane = threadIdx.x;
    const int base = 8 * lane;  // my cols are base+1 .. base+8 (1-indexed)

    for (int k = lane; k <= HN; k += 64) {
        u_s[k] = 0.0f;
        p_s[k] = 0;
        way_s[k] = 0;
    }
    __syncthreads();

    float v[8];
#pragma unroll
    for (int k = 0; k < 8; ++k) v[k] = 0.0f;

    for (int i = 1; i <= HN; ++i) {
        if (lane == 0) p_s[0] = i;

        int p_own[8];
        float u_own[8];
        float minv[8];
        int way[8];
#pragma unroll
        for (int k = 0; k < 8; ++k) p_own[k] = p_s[base + k + 1];
#pragma unroll
        for (int k = 0; k < 8; ++k) u_own[k] = u_s[p_own[k]];
#pragma unroll
        for (int k = 0; k < 8; ++k) {
            minv[k] = HINF;
            way[k] = 0;
        }
        unsigned usedmask = 0u;
        float u_i_run = u_s[i];  // running u[i] (col 0 is always used: u[p[0]] += delta)
        float u_cur = u_i_run;   // u[i0] for the current iteration
        int j0 = 0;
        int i0 = i;
        int jfin = 0;

        // preload row i0 = i
        const float* rowp = cost + (size_t)(i0 - 1) * HN + base;
        float4 ra = *reinterpret_cast<const float4*>(rowp);
        float4 rb = *reinterpret_cast<const float4*>(rowp + 4);

        while (true) {
            // used[j0] = True (col 0 is virtual, no owner)
            if (j0 != 0) {
                int k0 = j0 - 1;
                if ((k0 >> 3) == lane) usedmask |= 1u << (k0 & 7);
            }

            float c8[8] = {ra.x, ra.y, ra.z, ra.w, rb.x, rb.y, rb.z, rb.w};
#pragma unroll
            for (int k = 0; k < 8; ++k) {
                // cur = costp[i0][j] - u[i0] - v[j], costp = -cost (exact)
                float cur = (-c8[k] - u_cur) - v[k];
                bool fr = !((usedmask >> k) & 1u);
                if (fr && (cur < minv[k])) {
                    minv[k] = cur;
                    way[k] = j0;
                }
            }

            // local lexicographic argmin over my 8 cols (ascending index = first-min)
            float tv[8];
            int tj[8];
            float tu[8];
#pragma unroll
            for (int k = 0; k < 8; ++k) {
                bool used = (usedmask >> k) & 1u;
                tv[k] = used ? HINF : minv[k];
                tj[k] = ((base + k + 1) << 16) | p_own[k];  // (col j << 16) | matched row
                tu[k] = u_own[k];
            }
#pragma unroll
            for (int s = 1; s < 8; s <<= 1) {
#pragma unroll
                for (int k = 0; k < 8; k += 2 * s) {
                    bool take =
                        (tv[k + s] < tv[k]) || ((tv[k + s] == tv[k]) && (tj[k + s] < tj[k]));
                    if (take) {
                        tv[k] = tv[k + s];
                        tj[k] = tj[k + s];
                        tu[k] = tu[k + s];
                    }
                }
            }
            float bv = tv[0];
            int bj = tj[0];
            float bu = tu[0];

            // wave-wide lexicographic argmin via DPP, result lands in lane 63
            DPP_STEP(0x111)  // row_shr:1
            DPP_STEP(0x112)  // row_shr:2
            DPP_STEP(0x114)  // row_shr:4
            DPP_STEP(0x118)  // row_shr:8
            DPP_STEP(0x142)  // row_bcast15
            DPP_STEP(0x143)  // row_bcast31

            int rvi = __builtin_amdgcn_readlane(__float_as_int(bv), 63);
            int rji = __builtin_amdgcn_readlane(bj, 63);
            int rui = __builtin_amdgcn_readlane(__float_as_int(bu), 63);
            const float delta = __int_as_float(rvi);
            const int j1 = rji >> 16;
            const int prow = rji & 0xFFFF;
            const bool fin = (prow == 0);

            // issue next row's load BEFORE the bookkeeping VALU (hide L2 latency)
            if (!fin) {
                rowp = cost + (size_t)(prow - 1) * HN + base;
                ra = *reinterpret_cast<const float4*>(rowp);
                rb = *reinterpret_cast<const float4*>(rowp + 4);
            }

            // dual updates, exactly one fp add/sub per entry as in the reference
            u_i_run += delta;
#pragma unroll
            for (int k = 0; k < 8; ++k) {
                if ((usedmask >> k) & 1u) {
                    v[k] -= delta;
                    u_own[k] += delta;  // register-sequential, bit-identical to LDS adds
                } else {
                    minv[k] -= delta;
                }
            }

            if (fin) {
                jfin = j1;
                break;
            }
            j0 = j1;
            i0 = prow;
            u_cur = __int_as_float(rui);  // u[p[j1]]: phase-invariant while col was free
        }

        // dump way, write back duals of used cols' rows (+ row i), then augment
#pragma unroll
        for (int k = 0; k < 8; ++k) {
            way_s[base + k + 1] = way[k];
            if ((usedmask >> k) & 1u) u_s[p_own[k]] = u_own[k];
        }
        if (lane == 0) u_s[i] = u_i_run;
        __syncthreads();
        if (lane == 0) {
            int jw = jfin;
            while (jw != 0) {
                int jn = way_s[jw];
                p_s[jw] = p_s[jn];
                jw = jn;
            }
        }
        __syncthreads();
    }

    // outputs: [cost (512x512)] [row_ind (512)] [col_ind (512)] as float32
    float* rowo = out + HN * HN;
    float* colo = rowo + HN;
#pragma unroll
    for (int k = 0; k < 8; ++k) {
        int r = base + k;
        rowo[r] = (float)r;
        int prow = p_s[r + 1];  // row matched to col r+1 (1-indexed)
        colo[prow - 1] = (float)r;
    }
}

extern "C" void kernel_launch(void* const* d_in, const int* in_sizes, int n_in,
                              void* d_out, int out_size, void* d_ws, size_t ws_size,
                              hipStream_t stream) {
    const float* sim = (const float*)d_in[0];
    const float* iou = (const float*)d_in[1];
    float* out = (float*)d_out;

    cost_add_kernel<<<(HN * HN / 4 + 255) / 256, 256, 0, stream>>>(sim, iou, out);
    hungarian_kernel<<<1, 64, 0, stream>>>(out, out);
}

// Round 3
// 5265.514 us; speedup vs baseline: 2.2161x; 1.9079x over previous
//
#include <hip/hip_runtime.h>

static constexpr int HN = 512;
static constexpr float HINF = 1e9f;

// cost = sim + iou (exact fp32 add, matches jnp)
__global__ void cost_add_kernel(const float* __restrict__ sim,
                                const float* __restrict__ iou,
                                float* __restrict__ cost) {
    int idx = blockIdx.x * blockDim.x + threadIdx.x;
    if (idx < HN * HN / 4) {
        const float4* s4 = reinterpret_cast<const float4*>(sim);
        const float4* i4 = reinterpret_cast<const float4*>(iou);
        float4 a = s4[idx];
        float4 b = i4[idx];
        float4 c;
        c.x = a.x + b.x;
        c.y = a.y + b.y;
        c.z = a.z + b.z;
        c.w = a.w + b.w;
        reinterpret_cast<float4*>(cost)[idx] = c;
    }
}

// value-only wave-min step: combine with value shifted in from lower lanes
#define DPPMIN(ctrl)                                                                          \
    {                                                                                         \
        int _mi = __builtin_amdgcn_update_dpp(__float_as_int(m), __float_as_int(m), (ctrl),   \
                                              0xF, 0xF, false);                               \
        m = fminf(m, __int_as_float(_mi));                                                    \
    }

// Exact mirror of the reference JV (e-maxx) Hungarian on -cost. Single wave of 64 lanes,
// lane owns 8 consecutive cols. Inner loop: no LDS; value-only DPP min + ballot/ff1 winner
// recovery; dual updates use the reference's own +/-0.0 vectorized semantics (bit-exact).
__global__ void __launch_bounds__(64, 1) hungarian_kernel(const float* __restrict__ cost,
                                                          float* __restrict__ out) {
    __shared__ float u_s[HN + 1];
    __shared__ int p_s[HN + 1];
    __shared__ int way_t[HN];  // transposed: col j at [( (j-1)&7 )*64 + ((j-1)>>3)]

    const int lane = threadIdx.x;
    const int base = 8 * lane;  // cols base+1 .. base+8 (1-indexed)

    for (int k = lane; k <= HN; k += 64) {
        u_s[k] = 0.0f;
        p_s[k] = 0;
    }
    __syncthreads();

    float v[8];
#pragma unroll
    for (int k = 0; k < 8; ++k) v[k] = 0.0f;

    for (int i = 1; i <= HN; ++i) {
        // preload row i (i0 = p[0] = i)
        const float4* r4 = reinterpret_cast<const float4*>(cost + ((size_t)(i - 1) << 9));
        float4 ra = r4[2 * lane];
        float4 rb = r4[2 * lane + 1];

        int p8[8];
        float u_own[8];
        int tjb[8];
#pragma unroll
        for (int k = 0; k < 8; ++k) p8[k] = p_s[base + k + 1];
#pragma unroll
        for (int k = 0; k < 8; ++k) u_own[k] = u_s[p8[k]];
#pragma unroll
        for (int k = 0; k < 8; ++k) tjb[k] = ((base + k + 1) << 10) | p8[k];
        float u_i_run = u_s[i];
        float u_cur = u_i_run;

        float minv[8];
        int way[8];
#pragma unroll
        for (int k = 0; k < 8; ++k) {
            minv[k] = HINF;
            way[k] = 0;
        }
        unsigned usedmask = 0u;
        int j0 = 0;
        int jfin = 0;

        if (lane == 0) p_s[0] = i;  // augment reads p_s[0] at path end

        while (true) {
            // mark j0 used (no-op when j0 == 0: lane index becomes huge)
            unsigned km1 = (unsigned)(j0 - 1);
            if ((unsigned)lane == (km1 >> 3)) usedmask |= (1u << (km1 & 7u));

            float c8[8] = {ra.x, ra.y, ra.z, ra.w, rb.x, rb.y, rb.z, rb.w};
            float tv[8];
#pragma unroll
            for (int k = 0; k < 8; ++k) {
                float t = (-c8[k]) - u_cur;  // (costp - u), costp = -cost
                float cur = t - v[k];        // ... - v
                bool fr = !((usedmask >> k) & 1u);
                bool better = fr && (cur < minv[k]);
                minv[k] = better ? cur : minv[k];
                way[k] = better ? j0 : way[k];
                tv[k] = fr ? minv[k] : HINF;  // cand = where(free, minv, INF)
            }

            // local 8->1 first-min tree (strict <, left/lower-col wins ties)
            float av[4];
            int aj[4];
            float au[4];
#pragma unroll
            for (int k = 0; k < 4; ++k) {
                bool r = tv[2 * k + 1] < tv[2 * k];
                av[k] = r ? tv[2 * k + 1] : tv[2 * k];
                aj[k] = r ? tjb[2 * k + 1] : tjb[2 * k];
                au[k] = r ? u_own[2 * k + 1] : u_own[2 * k];
            }
            float bv2[2];
            int bj2[2];
            float bu2[2];
#pragma unroll
            for (int k = 0; k < 2; ++k) {
                bool r = av[2 * k + 1] < av[2 * k];
                bv2[k] = r ? av[2 * k + 1] : av[2 * k];
                bj2[k] = r ? aj[2 * k + 1] : aj[2 * k];
                bu2[k] = r ? au[2 * k + 1] : au[2 * k];
            }
            bool r0 = bv2[1] < bv2[0];
            float lv = r0 ? bv2[1] : bv2[0];
            int lj = r0 ? bj2[1] : bj2[0];
            float lu = r0 ? bu2[1] : bu2[0];

            // wave-wide min (value only), result in lane 63
            float m = lv;
            DPPMIN(0x111)  // row_shr:1
            DPPMIN(0x112)  // row_shr:2
            DPPMIN(0x114)  // row_shr:4
            DPPMIN(0x118)  // row_shr:8
            DPPMIN(0x142)  // row_bcast15
            DPPMIN(0x143)  // row_bcast31
            float gmin = __int_as_float(__builtin_amdgcn_readlane(__float_as_int(m), 63));

            // first lane achieving the min owns the global first argmin
            unsigned long long eq = __ballot(lv == gmin);
            int lanestar = __ffsll(eq) - 1;
            int tj0 = __builtin_amdgcn_readlane(lj, lanestar);
            float tu0 = __int_as_float(__builtin_amdgcn_readlane(__float_as_int(lu), lanestar));

            int j1 = tj0 >> 10;
            int prow = tj0 & 1023;

            // issue next row load early (uniform scalar base + per-lane const offset)
            if (prow != 0) {
                const float4* q4 =
                    reinterpret_cast<const float4*>(cost + ((size_t)(prow - 1) << 9));
                ra = q4[2 * lane];
                rb = q4[2 * lane + 1];
            }

            // dual updates — reference's vectorized semantics, incl. +/-0.0 on non-used
            float vdelta = gmin;
#pragma unroll
            for (int k = 0; k < 8; ++k) {
                bool uk = (usedmask >> k) & 1u;
                float dv = uk ? vdelta : 0.0f;
                float dm = uk ? 0.0f : vdelta;
                v[k] -= dv;        // v = v - where(used, d, 0)
                minv[k] -= dm;     // minv = where(used, minv, minv - d)  (x-0.0 == x bitwise)
                u_own[k] += dv;    // u[p] += where(used, d, 0)
            }
            u_i_run += gmin;       // used[0] is always true

            if (prow == 0) {
                jfin = j1;
                break;
            }
            j0 = j1;
            u_cur = tu0;  // u[p[j1]] — unchanged this phase while col j1 was free
        }

        // dump way (conflict-free transposed), write back duals of used cols' rows
#pragma unroll
        for (int k = 0; k < 8; ++k) {
            way_t[k * 64 + lane] = way[k];
            if ((usedmask >> k) & 1u) u_s[p8[k]] = u_own[k];
        }
        if (lane == 0) u_s[i] = u_i_run;
        __syncthreads();
        if (lane == 0) {
            int jw = jfin;
            while (jw != 0) {
                int jn = way_t[((jw - 1) & 7) * 64 + ((jw - 1) >> 3)];
                p_s[jw] = p_s[jn];
                jw = jn;
            }
        }
        __syncthreads();
    }

    // outputs: [cost (512x512)] [row_ind (512)] [col_ind (512)] as float32
    float* rowo = out + HN * HN;
    float* colo = rowo + HN;
#pragma unroll
    for (int k = 0; k < 8; ++k) {
        int r = base + k;
        rowo[r] = (float)r;
        int prow = p_s[r + 1];
        colo[prow - 1] = (float)r;
    }
}

extern "C" void kernel_launch(void* const* d_in, const int* in_sizes, int n_in,
                              void* d_out, int out_size, void* d_ws, size_t ws_size,
                              hipStream_t stream) {
    const float* sim = (const float*)d_in[0];
    const float* iou = (const float*)d_in[1];
    float* out = (float*)d_out;

    cost_add_kernel<<<(HN * HN / 4 + 255) / 256, 256, 0, stream>>>(sim, iou, out);
    hungarian_kernel<<<1, 64, 0, stream>>>(out, out);
}